// Round 4
// baseline (118.494 us; speedup 1.0000x reference)
//
#include <hip/hip_runtime.h>

constexpr int N  = 128;
constexpr int C  = 2048;
constexpr int KP = 4;
constexpr int KN = 508;
constexpr int K  = 512;    // KP + KN
constexpr int NK = N * K;  // 65536 gathers
constexpr int NB = 1024;   // sort buckets over index space [0, 50000)
constexpr int BKT_W = 49;  // ceil(50000 / 1024)

// ws layout (ints/floats):
//   bins   : [0, NB)
//   offs   : [NB, 2*NB)          (scan result; mutated by scatter, rebuilt each call)
//   sorted : [2*NB, 2*NB+NK)     packed (n<<9|k), idx-bucket-sorted
//   rloss  : floats after that

__device__ __forceinline__ int gather_idx(const int* pos_idx, const int* neg_idx, int n, int k) {
    return (k < KP) ? pos_idx[n * KP + k] : neg_idx[n * KN + (k - KP)];
}

__global__ __launch_bounds__(1024) void zero_bins_kernel(int* __restrict__ bins) {
    bins[threadIdx.x] = 0;
}

__global__ __launch_bounds__(256) void hist_kernel(
    const int* __restrict__ pos_idx, const int* __restrict__ neg_idx,
    int* __restrict__ bins)
{
    const int t = blockIdx.x * 256 + threadIdx.x;   // 0..NK
    const int n = t >> 9, k = t & (K - 1);
    const int idx = gather_idx(pos_idx, neg_idx, n, k);
    atomicAdd(&bins[idx / BKT_W], 1);
}

// single-block exclusive scan of 1024 bins (Hillis-Steele in LDS)
__global__ __launch_bounds__(1024) void scan_kernel(
    const int* __restrict__ bins, int* __restrict__ offs)
{
    __shared__ int s[NB];
    const int t = threadIdx.x;
    s[t] = bins[t];
    __syncthreads();
    #pragma unroll
    for (int d = 1; d < NB; d <<= 1) {
        int v = (t >= d) ? s[t - d] : 0;
        __syncthreads();
        s[t] += v;
        __syncthreads();
    }
    offs[t] = (t == 0) ? 0 : s[t - 1];   // exclusive
}

__global__ __launch_bounds__(256) void scatter_kernel(
    const int* __restrict__ pos_idx, const int* __restrict__ neg_idx,
    int* __restrict__ offs, int* __restrict__ sorted)
{
    const int t = blockIdx.x * 256 + threadIdx.x;
    const int n = t >> 9, k = t & (K - 1);
    const int idx = gather_idx(pos_idx, neg_idx, n, k);
    const int p = atomicAdd(&offs[idx / BKT_W], 1);
    sorted[p] = (n << 9) | k;
}

// One wave per gather, processed in idx-sorted order so duplicate rows of M
// are temporally adjacent -> L3 hits. Output location is (n,k)-unique, so
// the (atomic-order-dependent) within-bucket permutation doesn't change values.
__global__ __launch_bounds__(256) void logits_kernel(
    const float* __restrict__ inputs,
    const int*   __restrict__ pos_idx,
    const int*   __restrict__ neg_idx,
    const float* __restrict__ M,
    const int*   __restrict__ sorted,
    float*       __restrict__ logits)
{
    const int wave = threadIdx.x >> 6;
    const int lane = threadIdx.x & 63;
    const int pos  = blockIdx.x * 4 + wave;

    const int packed = sorted[pos];
    const int n = packed >> 9, k = packed & (K - 1);
    const int idx = gather_idx(pos_idx, neg_idx, n, k);

    const float4* __restrict__ a = reinterpret_cast<const float4*>(inputs + (size_t)n * C);
    const float4* __restrict__ b = reinterpret_cast<const float4*>(M + (size_t)idx * C);

    float acc = 0.f;
    #pragma unroll
    for (int i = 0; i < C / (4 * 64); ++i) {   // 8 iters, 16 B/lane
        float4 av = a[i * 64 + lane];
        float4 bv = b[i * 64 + lane];
        acc = fmaf(av.x, bv.x, acc);
        acc = fmaf(av.y, bv.y, acc);
        acc = fmaf(av.z, bv.z, acc);
        acc = fmaf(av.w, bv.w, acc);
    }

    #pragma unroll
    for (int off = 32; off > 0; off >>= 1)
        acc += __shfl_down(acc, off, 64);

    if (lane == 0) logits[n * K + k] = acc;
}

__global__ __launch_bounds__(512) void softmax_loss_kernel(
    const float* __restrict__ logits,
    const float* __restrict__ cof,
    float*       __restrict__ row_loss)
{
    __shared__ float red[8];
    __shared__ float xs[KP];
    const int n    = blockIdx.x;
    const int t    = threadIdx.x;
    const int wid  = t >> 6;
    const int lane = t & 63;

    float x = logits[n * K + t];

    float m = x;
    #pragma unroll
    for (int off = 1; off < 64; off <<= 1)
        m = fmaxf(m, __shfl_xor(m, off, 64));
    if (lane == 0) red[wid] = m;
    __syncthreads();
    float bm = red[0];
    #pragma unroll
    for (int i = 1; i < 8; ++i) bm = fmaxf(bm, red[i]);

    float s = expf(x - bm);
    #pragma unroll
    for (int off = 1; off < 64; off <<= 1)
        s += __shfl_xor(s, off, 64);
    __syncthreads();
    if (lane == 0) red[wid] = s;
    if (t < KP) xs[t] = x;
    __syncthreads();

    if (t == 0) {
        float bs = 0.f;
        #pragma unroll
        for (int i = 0; i < 8; ++i) bs += red[i];
        const float logZ = bm + logf(bs);
        float acc = 0.f;
        #pragma unroll
        for (int j = 0; j < KP; ++j)
            acc += cof[j] * (xs[j] - logZ);
        row_loss[n] = acc;
    }
}

__global__ __launch_bounds__(128) void loss_reduce_kernel(
    const float* __restrict__ row_loss,
    float*       __restrict__ out)
{
    const int t = threadIdx.x;
    float v = row_loss[t];
    #pragma unroll
    for (int off = 1; off < 64; off <<= 1)
        v += __shfl_xor(v, off, 64);
    __shared__ float red[2];
    if ((t & 63) == 0) red[t >> 6] = v;
    __syncthreads();
    if (t == 0) out[0] = -(red[0] + red[1]) / (float)N;
}

extern "C" void kernel_launch(void* const* d_in, const int* in_sizes, int n_in,
                              void* d_out, int out_size, void* d_ws, size_t ws_size,
                              hipStream_t stream) {
    const float* inputs  = (const float*)d_in[0];
    const int*   pos_idx = (const int*)d_in[1];
    const int*   neg_idx = (const int*)d_in[2];
    const float* cof     = (const float*)d_in[3];
    const float* M       = (const float*)d_in[4];

    float* out    = (float*)d_out;
    float* logits = out + 1;            // d_out = [loss(1), logits(128*512)]

    int*   bins     = (int*)d_ws;
    int*   offs     = bins + NB;
    int*   sorted   = offs + NB;
    float* row_loss = (float*)(sorted + NK);

    zero_bins_kernel<<<1, NB, 0, stream>>>(bins);
    hist_kernel<<<NK / 256, 256, 0, stream>>>(pos_idx, neg_idx, bins);
    scan_kernel<<<1, NB, 0, stream>>>(bins, offs);
    scatter_kernel<<<NK / 256, 256, 0, stream>>>(pos_idx, neg_idx, offs, sorted);
    logits_kernel<<<NK / 4, 256, 0, stream>>>(inputs, pos_idx, neg_idx, M, sorted, logits);
    softmax_loss_kernel<<<N, K, 0, stream>>>(logits, cof, row_loss);
    loss_reduce_kernel<<<1, N, 0, stream>>>(row_loss, out);
}

// Round 5
// 100.802 us; speedup vs baseline: 1.1755x; 1.1755x over previous
//
#include <hip/hip_runtime.h>

constexpr int N  = 128;
constexpr int C  = 2048;
constexpr int KP = 4;
constexpr int KN = 508;
constexpr int K  = 512;            // KP + KN
constexpr int NPASS = 4;           // K-dim slices; per-pass unique M footprint ~73 MB << 256 MB L3
constexpr int SL = C / NPASS;      // 512 floats per slice

// One wave computes a partial dot over C-slice [k0, k0+SL) for one gather.
// Running the gather 4x over K-slices keeps each pass's unique M-row-slice
// set L3-resident, so duplicate gathers hit L3 instead of re-fetching HBM.
__global__ __launch_bounds__(256) void logits_slice_kernel(
    const float* __restrict__ inputs,
    const int*   __restrict__ pos_idx,
    const int*   __restrict__ neg_idx,
    const float* __restrict__ M,
    float*       __restrict__ logits,
    int k0, int first)
{
    const int wave = threadIdx.x >> 6;
    const int lane = threadIdx.x & 63;
    const int n    = blockIdx.y;
    const int k    = (blockIdx.x << 2) + wave;

    const int idx = (k < KP) ? pos_idx[n * KP + k]
                             : neg_idx[n * KN + (k - KP)];

    const float4* __restrict__ a = reinterpret_cast<const float4*>(inputs + (size_t)n * C + k0);
    const float4* __restrict__ b = reinterpret_cast<const float4*>(M + (size_t)idx * C + k0);

    float acc = 0.f;
    #pragma unroll
    for (int i = 0; i < SL / (4 * 64); ++i) {   // 2 iters, 16 B/lane each
        float4 av = a[i * 64 + lane];
        float4 bv = b[i * 64 + lane];
        acc = fmaf(av.x, bv.x, acc);
        acc = fmaf(av.y, bv.y, acc);
        acc = fmaf(av.z, bv.z, acc);
        acc = fmaf(av.w, bv.w, acc);
    }

    #pragma unroll
    for (int off = 32; off > 0; off >>= 1)
        acc += __shfl_down(acc, off, 64);

    if (lane == 0) {
        float* p = &logits[n * K + k];
        *p = first ? acc : (*p + acc);   // passes are stream-ordered -> deterministic
    }
}

// One block per row n: log-softmax denominator over K=512, then the
// weighted positive-logit partial loss for this row (deterministic).
__global__ __launch_bounds__(512) void softmax_loss_kernel(
    const float* __restrict__ logits,
    const float* __restrict__ cof,
    float*       __restrict__ row_loss)
{
    __shared__ float red[8];
    __shared__ float xs[KP];
    const int n    = blockIdx.x;
    const int t    = threadIdx.x;
    const int wid  = t >> 6;
    const int lane = t & 63;

    float x = logits[n * K + t];

    float m = x;
    #pragma unroll
    for (int off = 1; off < 64; off <<= 1)
        m = fmaxf(m, __shfl_xor(m, off, 64));
    if (lane == 0) red[wid] = m;
    __syncthreads();
    float bm = red[0];
    #pragma unroll
    for (int i = 1; i < 8; ++i) bm = fmaxf(bm, red[i]);

    float s = expf(x - bm);
    #pragma unroll
    for (int off = 1; off < 64; off <<= 1)
        s += __shfl_xor(s, off, 64);
    __syncthreads();
    if (lane == 0) red[wid] = s;
    if (t < KP) xs[t] = x;
    __syncthreads();

    if (t == 0) {
        float bs = 0.f;
        #pragma unroll
        for (int i = 0; i < 8; ++i) bs += red[i];
        const float logZ = bm + logf(bs);
        float acc = 0.f;
        #pragma unroll
        for (int j = 0; j < KP; ++j)
            acc += cof[j] * (xs[j] - logZ);
        row_loss[n] = acc;   // = sum_j cof[j] * logp[n, j]
    }
}

// Single block: deterministic fixed-order reduction of 128 row losses.
__global__ __launch_bounds__(128) void loss_reduce_kernel(
    const float* __restrict__ row_loss,
    float*       __restrict__ out)
{
    const int t = threadIdx.x;
    float v = row_loss[t];
    #pragma unroll
    for (int off = 1; off < 64; off <<= 1)
        v += __shfl_xor(v, off, 64);
    __shared__ float red[2];
    if ((t & 63) == 0) red[t >> 6] = v;
    __syncthreads();
    if (t == 0) out[0] = -(red[0] + red[1]) / (float)N;
}

extern "C" void kernel_launch(void* const* d_in, const int* in_sizes, int n_in,
                              void* d_out, int out_size, void* d_ws, size_t ws_size,
                              hipStream_t stream) {
    const float* inputs  = (const float*)d_in[0];
    const int*   pos_idx = (const int*)d_in[1];
    const int*   neg_idx = (const int*)d_in[2];
    const float* cof     = (const float*)d_in[3];
    const float* M       = (const float*)d_in[4];

    float* out      = (float*)d_out;
    float* logits   = out + 1;          // d_out = [loss(1), logits(128*512)]
    float* row_loss = (float*)d_ws;     // 128 floats of scratch

    for (int p = 0; p < NPASS; ++p) {
        logits_slice_kernel<<<dim3(K / 4, N), 256, 0, stream>>>(
            inputs, pos_idx, neg_idx, M, logits, p * SL, p == 0 ? 1 : 0);
    }
    softmax_loss_kernel<<<N, K, 0, stream>>>(logits, cof, row_loss);
    loss_reduce_kernel<<<1, N, 0, stream>>>(row_loss, out);
}

// Round 7
// 83.979 us; speedup vs baseline: 1.4110x; 1.2003x over previous
//
#include <hip/hip_runtime.h>

constexpr int N    = 128;
constexpr int C    = 2048;
constexpr int KP   = 4;
constexpr int KN   = 508;
constexpr int K    = 512;     // KP + KN
constexpr int NK   = N * K;   // 65536 gathers
constexpr int NC   = 50000;   // memory bank rows
constexpr int MAXD = 16;      // slots per idx (P(overflow) ~ 1e-8, handled anyway)
constexpr int OCAP = 512;     // overflow list capacity

// ws layout (ints): count[NC] | pairs[NC*MAXD] | ocount[1] | overflow[OCAP] | row_loss(f32)[N]

__device__ __forceinline__ int gather_idx(const int* pos_idx, const int* neg_idx, int n, int k) {
    return (k < KP) ? pos_idx[n * KP + k] : neg_idx[n * KN + (k - KP)];
}

__global__ __launch_bounds__(256) void zero_kernel(int* __restrict__ count, int* __restrict__ ocount) {
    const int t = blockIdx.x * 256 + threadIdx.x;
    if (t < NC) count[t] = 0;
    if (t == 0) *ocount = 0;
}

// Append each (n,k) pair to its idx's slot list. 50000 bins, avg 1.3
// entries/bin -> negligible atomic contention (round-4's 1024 bins had
// 64-deep serial chains; that was the cost there, not the idea).
__global__ __launch_bounds__(256) void build_kernel(
    const int* __restrict__ pos_idx, const int* __restrict__ neg_idx,
    int* __restrict__ count, int* __restrict__ pairs,
    int* __restrict__ ocount, int* __restrict__ overflow)
{
    const int t = blockIdx.x * 256 + threadIdx.x;   // < NK
    const int n = t >> 9, k = t & (K - 1);
    const int idx = gather_idx(pos_idx, neg_idx, n, k);
    const int packed = (n << 9) | k;
    const int p = atomicAdd(&count[idx], 1);
    if (p < MAXD) {
        pairs[idx * MAXD + p] = packed;
    } else {
        const int o = atomicAdd(ocount, 1);
        if (o < OCAP) overflow[o] = (idx << 16) | packed;
    }
}

// One wave per M row: load the 8 KB row into registers ONCE, then serve all
// (n,k) pairs that gather it. M traffic = unique rows only (structural dedup,
// no cache-timing dependence). inputs (1 MB) is L2-resident.
__global__ __launch_bounds__(256) void gemv_dedup_kernel(
    const float* __restrict__ inputs,
    const float* __restrict__ M,
    const int*   __restrict__ count,
    const int*   __restrict__ pairs,
    const int*   __restrict__ ocount,
    const int*   __restrict__ overflow,
    float*       __restrict__ logits)
{
    const int wave = threadIdx.x >> 6;
    const int lane = threadIdx.x & 63;
    const int idx  = blockIdx.x * 4 + wave;
    if (idx >= NC) return;

    const int cnt = count[idx];
    if (cnt == 0) return;

    const float4* __restrict__ b = reinterpret_cast<const float4*>(M + (size_t)idx * C);
    float4 mrow[8];
    #pragma unroll
    for (int i = 0; i < 8; ++i) mrow[i] = b[i * 64 + lane];   // 16 B/lane x 8 = 8 KB/wave

    const float4* __restrict__ A = reinterpret_cast<const float4*>(inputs);

    auto dot_and_store = [&](int packed) {
        const int n = packed >> 9, k = packed & (K - 1);
        const float4* __restrict__ a = A + (size_t)n * (C / 4);
        float acc = 0.f;
        #pragma unroll
        for (int i = 0; i < 8; ++i) {
            float4 av = a[i * 64 + lane];
            float4 bv = mrow[i];
            acc = fmaf(av.x, bv.x, acc);
            acc = fmaf(av.y, bv.y, acc);
            acc = fmaf(av.z, bv.z, acc);
            acc = fmaf(av.w, bv.w, acc);
        }
        #pragma unroll
        for (int off = 32; off > 0; off >>= 1)
            acc += __shfl_down(acc, off, 64);
        if (lane == 0) logits[n * K + k] = acc;
    };

    const int lim = cnt < MAXD ? cnt : MAXD;
    for (int j = 0; j < lim; ++j)
        dot_and_store(pairs[idx * MAXD + j]);

    if (cnt > MAXD) {   // ~never: scan the tiny overflow list for our idx
        const int oc = min(*ocount, OCAP);
        for (int i = 0; i < oc; ++i) {
            const int e = overflow[i];
            if ((e >> 16) == idx) dot_and_store(e & 0xFFFF);
        }
    }
}

// Fallback (round-2 structure) if ws is too small for the pair lists.
__global__ __launch_bounds__(256) void logits_kernel(
    const float* __restrict__ inputs,
    const int*   __restrict__ pos_idx,
    const int*   __restrict__ neg_idx,
    const float* __restrict__ M,
    float*       __restrict__ logits)
{
    const int wave = threadIdx.x >> 6;
    const int lane = threadIdx.x & 63;
    const int n    = blockIdx.y;
    const int k    = (blockIdx.x << 2) + wave;

    const int idx = (k < KP) ? pos_idx[n * KP + k]
                             : neg_idx[n * KN + (k - KP)];

    const float4* __restrict__ a = reinterpret_cast<const float4*>(inputs + (size_t)n * C);
    const float4* __restrict__ b = reinterpret_cast<const float4*>(M + (size_t)idx * C);

    float acc = 0.f;
    #pragma unroll
    for (int i = 0; i < C / (4 * 64); ++i) {
        float4 av = a[i * 64 + lane];
        float4 bv = b[i * 64 + lane];
        acc = fmaf(av.x, bv.x, acc);
        acc = fmaf(av.y, bv.y, acc);
        acc = fmaf(av.z, bv.z, acc);
        acc = fmaf(av.w, bv.w, acc);
    }
    #pragma unroll
    for (int off = 32; off > 0; off >>= 1)
        acc += __shfl_down(acc, off, 64);
    if (lane == 0) logits[n * K + k] = acc;
}

__global__ __launch_bounds__(512) void softmax_loss_kernel(
    const float* __restrict__ logits,
    const float* __restrict__ cof,
    float*       __restrict__ row_loss)
{
    __shared__ float red[8];
    __shared__ float xs[KP];
    const int n    = blockIdx.x;
    const int t    = threadIdx.x;
    const int wid  = t >> 6;
    const int lane = t & 63;

    float x = logits[n * K + t];

    float m = x;
    #pragma unroll
    for (int off = 1; off < 64; off <<= 1)
        m = fmaxf(m, __shfl_xor(m, off, 64));
    if (lane == 0) red[wid] = m;
    __syncthreads();
    float bm = red[0];
    #pragma unroll
    for (int i = 1; i < 8; ++i) bm = fmaxf(bm, red[i]);

    float s = expf(x - bm);
    #pragma unroll
    for (int off = 1; off < 64; off <<= 1)
        s += __shfl_xor(s, off, 64);
    __syncthreads();
    if (lane == 0) red[wid] = s;
    if (t < KP) xs[t] = x;
    __syncthreads();

    if (t == 0) {
        float bs = 0.f;
        #pragma unroll
        for (int i = 0; i < 8; ++i) bs += red[i];
        const float logZ = bm + logf(bs);
        float acc = 0.f;
        #pragma unroll
        for (int j = 0; j < KP; ++j)
            acc += cof[j] * (xs[j] - logZ);
        row_loss[n] = acc;
    }
}

__global__ __launch_bounds__(128) void loss_reduce_kernel(
    const float* __restrict__ row_loss,
    float*       __restrict__ out)
{
    const int t = threadIdx.x;
    float v = row_loss[t];
    #pragma unroll
    for (int off = 1; off < 64; off <<= 1)
        v += __shfl_xor(v, off, 64);
    __shared__ float red[2];
    if ((t & 63) == 0) red[t >> 6] = v;
    __syncthreads();
    if (t == 0) out[0] = -(red[0] + red[1]) / (float)N;
}

extern "C" void kernel_launch(void* const* d_in, const int* in_sizes, int n_in,
                              void* d_out, int out_size, void* d_ws, size_t ws_size,
                              hipStream_t stream) {
    const float* inputs  = (const float*)d_in[0];
    const int*   pos_idx = (const int*)d_in[1];
    const int*   neg_idx = (const int*)d_in[2];
    const float* cof     = (const float*)d_in[3];
    const float* M       = (const float*)d_in[4];

    float* out    = (float*)d_out;
    float* logits = out + 1;            // d_out = [loss(1), logits(128*512)]

    const size_t need = (size_t)(NC + NC * MAXD + 1 + OCAP + N) * 4;
    if (ws_size >= need) {
        int*   count    = (int*)d_ws;
        int*   pairs    = count + NC;
        int*   ocount   = pairs + (size_t)NC * MAXD;
        int*   overflow = ocount + 1;
        float* row_loss = (float*)(overflow + OCAP);

        zero_kernel<<<(NC + 255) / 256, 256, 0, stream>>>(count, ocount);
        build_kernel<<<NK / 256, 256, 0, stream>>>(pos_idx, neg_idx, count, pairs, ocount, overflow);
        gemv_dedup_kernel<<<(NC + 3) / 4, 256, 0, stream>>>(inputs, M, count, pairs, ocount, overflow, logits);
        softmax_loss_kernel<<<N, K, 0, stream>>>(logits, cof, row_loss);
        loss_reduce_kernel<<<1, N, 0, stream>>>(row_loss, out);
    } else {
        float* row_loss = (float*)d_ws;
        logits_kernel<<<dim3(K / 4, N), 256, 0, stream>>>(inputs, pos_idx, neg_idx, M, logits);
        softmax_loss_kernel<<<N, K, 0, stream>>>(logits, cof, row_loss);
        loss_reduce_kernel<<<1, N, 0, stream>>>(row_loss, out);
    }
}